// Round 1
// baseline (22278.349 us; speedup 1.0000x reference)
//
#include <hip/hip_runtime.h>
#include <hip/hip_fp16.h>
#include <cstdint>
#include <cstddef>

typedef _Float16 f16;
typedef _Float16 f16x8 __attribute__((ext_vector_type(8)));
typedef _Float16 f16x4 __attribute__((ext_vector_type(4)));
typedef float    f32x4 __attribute__((ext_vector_type(4)));

// ---------------- ws layout (bytes) ----------------
// Gs   f32 [2048][10]                :      0 ..  81920
// QM   f32 [10][16]                  :  81920 ..  82560
// CB   f32 [10][16]                  :  82560 ..  83200
// W1T  f16 [16][5][4][80]            :  83200 .. 134400
// WhhP f16 [57*10][64][8]            : 134400 .. 718080
// giP  f16 [2048][57][64][4]         : 718080 .. 60486912
#define WS_GS    0u
#define WS_QM    81920u
#define WS_CB    82560u
#define WS_W1T   83200u
#define WS_WHHP  134400u
#define WS_GIP   718080u

__device__ __forceinline__ float sigm_(float x){ return 1.0f/(1.0f + __expf(-x)); }
__device__ __forceinline__ float tanh_(float x){
  float ax = fabsf(x);
  float e  = __expf(-2.0f*ax);
  float r  = (1.0f - e)/(1.0f + e);
  return x < 0.0f ? -r : r;
}
__device__ __forceinline__ int imin_(int a,int b){ return a<b?a:b; }

// ================= K0: prep (QM, CB, W1T) =================
// QM[k][h] = sum_d q[k,d]*W1[2100+d,h] + m[k,d]*W1[2400+d,h]
// CB[b][h] = b1[h] + sum_d m[b,d]*W1[300+d,h] + q[b,d]*W1[600+d,h]
// W1T[h][blk][dg][ii] = W1[blkoff[blk] + dg*80+ii, h]  (f16, zero pad d>=300)
__global__ __launch_bounds__(512) void k0_prep(
    const float* __restrict__ q, const float* __restrict__ m,
    const float* __restrict__ W1, const float* __restrict__ b1,
    float* __restrict__ QM, float* __restrict__ CBo, f16* __restrict__ W1T)
{
  int tid = threadIdx.x;
  if (tid < 160){
    int k = tid >> 4, h = tid & 15;
    float acc = 0.f;
    for (int d = 0; d < 300; ++d)
      acc += q[k*300+d]*W1[(2100+d)*16+h] + m[k*300+d]*W1[(2400+d)*16+h];
    QM[tid] = acc;
  } else if (tid < 320){
    int b = (tid-160) >> 4, h = tid & 15;
    float acc = b1[h];
    for (int d = 0; d < 300; ++d)
      acc += m[b*300+d]*W1[(300+d)*16+h] + q[b*300+d]*W1[(600+d)*16+h];
    CBo[tid-160] = acc;
  }
  const int blkoff[5] = {0, 900, 1200, 1500, 1800};
  for (int i = tid; i < 25600; i += 512){
    int ii = i % 80; int r = i / 80;
    int dg = r % 4; r /= 4;
    int blk = r % 5; int h = r / 5;
    int d = dg*80 + ii;
    float v = 0.f;
    if (d < 300) v = W1[(blkoff[blk]+d)*16 + h];
    W1T[i] = (f16)v;
  }
}

// ================= Kpack: Whh -> MFMA A-fragment layout (f16) =================
// Tile mt = gate*19 + cb (M = gate-padded 3*304 = 912), K-chunk kc (K=320).
// A-frag: lane l holds A[row = l&15][k = (l>>4)*8 + e], row j' = mt*16+(l&15).
__global__ __launch_bounds__(64) void k_pack(const float* __restrict__ Whh, f16* __restrict__ WhhP)
{
  int bid = blockIdx.x, l = threadIdx.x;
  int mt = bid / 10, kc = bid % 10;
  int gate = mt / 19, cb = mt % 19;
  int rr = l & 15, grp = l >> 4;
  int c = cb*16 + rr;
  int j = gate*300 + imin_(c, 299);
  f16x8 v;
  #pragma unroll
  for (int e = 0; e < 8; ++e){
    int d = kc*32 + grp*8 + e;
    float x = Whh[(size_t)imin_(d,299)*900 + j];
    v[e] = (f16)((d < 300 && c < 300) ? x : 0.f);
  }
  *(f16x8*)&WhhP[((size_t)bid*64 + l)*8] = v;
}

// ================= K1: attention gate -> G[b][t] (d_out[0:20480]) =================
// One wave per t (8 waves/block, 256 blocks). Lane = (dg = l>>4 over d-ranges, lo = l&15 = h/k).
__global__ __launch_bounds__(512) void k1_attn(
    const float* __restrict__ cs, const float* __restrict__ mI, const float* __restrict__ qI,
    const float* __restrict__ mask, const float* __restrict__ Wb,
    const float* __restrict__ W2, const float* __restrict__ b2,
    const float* __restrict__ QMg, const float* __restrict__ CBg, const f16* __restrict__ W1Tg,
    float* __restrict__ Gout)
{
  __shared__ __align__(16) float q_s[3000];
  __shared__ __align__(16) float m_s[3000];
  __shared__ float Wb_s[3000];
  __shared__ float QM_s[160], CB_s[160], W2_s[16];
  __shared__ __align__(16) f16 W1T_s[25600];
  __shared__ float cwb_s[8][10][10];
  int tid = threadIdx.x;
  for (int i = tid; i < 3000; i += 512){ q_s[i] = qI[i]; m_s[i] = mI[i]; Wb_s[i] = Wb[i]; }
  for (int i = tid; i < 160; i += 512){ QM_s[i] = QMg[i]; CB_s[i] = CBg[i]; }
  if (tid < 16) W2_s[tid] = W2[tid];
  for (int i = tid; i < 25600; i += 512) W1T_s[i] = W1Tg[i];
  __syncthreads();

  int w = tid >> 6, l = tid & 63, dg = l >> 4, lo = l & 15;
  int t = blockIdx.x*8 + w;
  float a[10], cwb[10];
  #pragma unroll
  for (int b = 0; b < 10; ++b){ a[b] = 0.f; cwb[b] = 0.f; }

  for (int i = 0; i < 10; ++i){
    int d0 = dg*80 + i*8;
    const int wbase = lo*1600 + dg*80 + i*8;     // [h][blk][dg][ii], blk stride 320
    f16x8 wf0 = *(const f16x8*)&W1T_s[wbase + 0*320];
    f16x8 wf1 = *(const f16x8*)&W1T_s[wbase + 1*320];
    f16x8 wf2 = *(const f16x8*)&W1T_s[wbase + 2*320];
    f16x8 wf3 = *(const f16x8*)&W1T_s[wbase + 3*320];
    f16x8 wf4 = *(const f16x8*)&W1T_s[wbase + 4*320];
    int dc0 = imin_(d0, 296), dc1 = imin_(d0 + 4, 296);
    #pragma unroll
    for (int b = 0; b < 10; ++b){
      const float* csb = cs + ((size_t)t*10 + b)*300;
      float4 c0 = *(const float4*)(csb + dc0);
      float4 c1 = *(const float4*)(csb + dc1);
      float4 q0 = *(const float4*)(q_s + b*300 + dc0);
      float4 q1 = *(const float4*)(q_s + b*300 + dc1);
      float4 m0 = *(const float4*)(m_s + b*300 + dc0);
      float4 m1 = *(const float4*)(m_s + b*300 + dc1);
      float cv[8] = {c0.x,c0.y,c0.z,c0.w,c1.x,c1.y,c1.z,c1.w};
      float qv[8] = {q0.x,q0.y,q0.z,q0.w,q1.x,q1.y,q1.z,q1.w};
      float mv[8] = {m0.x,m0.y,m0.z,m0.w,m1.x,m1.y,m1.z,m1.w};
      #pragma unroll
      for (int e = 0; e < 8; ++e){
        int d = d0 + e;
        float cvv = cv[e];
        a[b] += cvv*(float)wf0[e] + (cvv*qv[e])*(float)wf1[e] + (cvv*mv[e])*(float)wf2[e]
              + fabsf(cvv - qv[e])*(float)wf3[e] + fabsf(cvv - mv[e])*(float)wf4[e];
        float wv = Wb_s[imin_(d, 299)*10 + imin_(lo, 9)];
        wv = (lo < 10 && d < 300) ? wv : 0.f;
        cwb[b] += cvv*wv;
      }
    }
  }
  // reduce cWb over dg groups -> lanes lo==k hold cWb[b][k]
  #pragma unroll
  for (int b = 0; b < 10; ++b){
    float v = cwb[b];
    v += __shfl_xor(v, 16, 64);
    v += __shfl_xor(v, 32, 64);
    cwb[b] = v;
  }
  if (dg == 0 && lo < 10){
    #pragma unroll
    for (int b = 0; b < 10; ++b) cwb_s[w][b][lo] = cwb[b];
  }
  __asm__ volatile("s_waitcnt lgkmcnt(0)" ::: "memory");
  __builtin_amdgcn_sched_barrier(0);
  float b2v = b2[0];
  #pragma unroll
  for (int b = 0; b < 10; ++b){
    float cross = 0.f;
    #pragma unroll
    for (int k = 0; k < 10; ++k) cross += cwb_s[w][b][k]*QM_s[k*16 + lo];
    float v = a[b];
    v += __shfl_xor(v, 16, 64);
    v += __shfl_xor(v, 32, 64);
    v += CB_s[b*16 + lo] + cross;
    float tv = tanh_(v)*W2_s[lo];
    tv += __shfl_xor(tv, 1, 64);
    tv += __shfl_xor(tv, 2, 64);
    tv += __shfl_xor(tv, 4, 64);
    tv += __shfl_xor(tv, 8, 64);
    a[b] = sigm_(tv + b2v);     // g
  }
  if (l == 0){
    #pragma unroll
    for (int b = 0; b < 10; ++b) Gout[b*2048 + t] = a[b]*mask[t*10 + b];
  }
}

// ================= K2: softmax over T per b: Gs[t][b] =================
__global__ __launch_bounds__(256) void k2_softmax(const float* __restrict__ G, float* __restrict__ Gs)
{
  int b = blockIdx.x, tid = threadIdx.x;
  __shared__ float red[4];
  float v[8];
  #pragma unroll
  for (int k = 0; k < 8; ++k) v[k] = G[b*2048 + tid + k*256];
  float mx = v[0];
  #pragma unroll
  for (int k = 1; k < 8; ++k) mx = fmaxf(mx, v[k]);
  #pragma unroll
  for (int off = 1; off < 64; off <<= 1) mx = fmaxf(mx, __shfl_xor(mx, off, 64));
  if ((tid & 63) == 0) red[tid >> 6] = mx;
  __syncthreads();
  mx = fmaxf(fmaxf(red[0], red[1]), fmaxf(red[2], red[3]));
  __syncthreads();
  float e[8], s = 0.f;
  #pragma unroll
  for (int k = 0; k < 8; ++k){ e[k] = __expf(v[k]-mx); s += e[k]; }
  #pragma unroll
  for (int off = 1; off < 64; off <<= 1) s += __shfl_xor(s, off, 64);
  if ((tid & 63) == 0) red[tid >> 6] = s;
  __syncthreads();
  s = red[0]+red[1]+red[2]+red[3];
  float inv = 1.0f / s;
  #pragma unroll
  for (int k = 0; k < 8; ++k) Gs[(tid + k*256)*10 + b] = e[k]*inv;
}

// ================= K3: gi[t] = seq[t] @ Wih + bih (+bhh folded for r,z) =================
// seq[t,b,d] = Gs[t, d%10] * cs[t, d%10, b*30 + d/10].  Output packed in MFMA C layout (f16).
__global__ __launch_bounds__(256) void k3_gi(
    const float* __restrict__ cs, const float* __restrict__ Gs,
    const float* __restrict__ Wih, const float* __restrict__ bih, const float* __restrict__ bhh,
    f16* __restrict__ giP)
{
  int t = blockIdx.x, tid = threadIdx.x;
  __shared__ __align__(16) float sfT[300*16];
  for (int i = tid; i < 3000; i += 256){
    int d = i / 10, bcol = i % 10;
    int jj = d % 10;
    sfT[d*16 + bcol] = Gs[t*10 + jj] * cs[((size_t)t*10 + jj)*300 + bcol*30 + d/10];
  }
  __syncthreads();
  float acc[4][10];
  #pragma unroll
  for (int jp = 0; jp < 4; ++jp)
    #pragma unroll
    for (int b = 0; b < 10; ++b) acc[jp][b] = 0.f;
  for (int d = 0; d < 300; ++d){
    float4 s0 = *(const float4*)&sfT[d*16 + 0];
    float4 s1 = *(const float4*)&sfT[d*16 + 4];
    float4 s2 = *(const float4*)&sfT[d*16 + 8];
    float sb[10] = {s0.x,s0.y,s0.z,s0.w, s1.x,s1.y,s1.z,s1.w, s2.x,s2.y};
    #pragma unroll
    for (int jp = 0; jp < 4; ++jp){
      int j = jp*256 + tid;
      float wv = Wih[(size_t)d*900 + imin_(j, 899)];
      wv = (j < 900) ? wv : 0.f;
      #pragma unroll
      for (int b = 0; b < 10; ++b) acc[jp][b] += wv * sb[b];
    }
  }
  #pragma unroll
  for (int jp = 0; jp < 4; ++jp){
    int j = jp*256 + tid;
    if (j < 900){
      int gate = j / 300, c = j - gate*300;
      int cb = c >> 4, rr = c & 15;
      int mt = gate*19 + cb, g = rr >> 2, er = rr & 3;
      float bias = bih[j] + (j < 600 ? bhh[j] : 0.f);
      size_t base = ((size_t)t*57 + mt)*256;
      #pragma unroll
      for (int b = 0; b < 10; ++b)
        giP[base + (size_t)(((g<<4)|b)*4 + er)] = (f16)(acc[jp][b] + bias);
    }
  }
}

// ================= K4: sequential GRU, single workgroup, MFMA f16 =================
// gh^T = WhhP(A, M=912 gate-padded) x hT(B, K=320, N=16).  8 waves own disjoint
// c-blocks (all 3 gates) -> gates are lane-local, no gh exchange.  h master f32 in regs.
__global__ __launch_bounds__(512) void k4_gru(
    const f16* __restrict__ WhhP, const f16* __restrict__ giP,
    const float* __restrict__ mI, const float* __restrict__ bhh, float* __restrict__ hout)
{
  __shared__ __align__(16) f16 Albuf[57*2*64*8];   // kc = 1,2  (116736 B)
  __shared__ __align__(16) f16 Bbuf[2][10*64*8];   // double-buffered hT f16 (2 x 10240 B)
  int tid = threadIdx.x;
  int w = tid >> 6, l = tid & 63, g = l >> 4, bl = l & 15;
  int ncb = (w < 5) ? 2 : 3;
  int cb0 = (w < 5) ? w*2 : 10 + (w-5)*3;

  {
    const uint4* src = (const uint4*)WhhP;
    uint4* dst = (uint4*)Albuf;
    for (int i = tid; i < 57*2*64; i += 512){
      int mt = i >> 7, rest = i & 127, kcl = rest >> 6, l2 = rest & 63;
      dst[i] = src[(mt*10 + 1 + kcl)*64 + l2];
    }
  }
  for (int i = tid; i < 640; i += 512){   // hT(B) init from m, zero pads (both buffers)
    int kc = i >> 6, l2 = i & 63, grp2 = (l2 >> 4) & 3, bc = l2 & 15;
    f16x8 v;
    #pragma unroll
    for (int e = 0; e < 8; ++e){
      int d = kc*32 + grp2*8 + e;
      float x = mI[imin_(bc,9)*300 + imin_(d,299)];
      v[e] = (f16)((d < 300 && bc < 10) ? x : 0.f);
    }
    *(f16x8*)&Bbuf[0][i*8] = v;
    *(f16x8*)&Bbuf[1][i*8] = v;
  }
  f16x8 areg[3][3];                        // kc = 0 resident
  #pragma unroll
  for (int cbl = 0; cbl < 3; ++cbl)
    #pragma unroll
    for (int gate = 0; gate < 3; ++gate){
      int mt = gate*19 + imin_(cb0 + cbl, 18);
      areg[cbl][gate] = *(const f16x8*)&WhhP[((size_t)(mt*10)*64 + l)*8];
    }
  float hreg[3][4], bhhN[3][4];
  #pragma unroll
  for (int cbl = 0; cbl < 3; ++cbl)
    #pragma unroll
    for (int rg = 0; rg < 4; ++rg){
      int c = (cb0 + cbl)*16 + g*4 + rg;
      bool okc = (cbl < ncb) && (c < 300);
      hreg[cbl][rg] = (okc && bl < 10) ? mI[imin_(bl,9)*300 + imin_(c,299)] : 0.f;
      bhhN[cbl][rg] = okc ? bhh[600 + imin_(c,299)] : 0.f;
    }
  __syncthreads();

  for (int t = 0; t < 2048; ++t){
    const f16* br = &Bbuf[t & 1][0];
    f16* bw = &Bbuf[(t & 1) ^ 1][0];
    f16x4 giv[3][3];
    #pragma unroll
    for (int cbl = 0; cbl < 3; ++cbl)
      #pragma unroll
      for (int gate = 0; gate < 3; ++gate){
        int mt = gate*19 + imin_(cb0 + cbl, 18);
        giv[cbl][gate] = *(const f16x4*)&giP[(((size_t)t*57 + mt)*64 + l)*4];
      }
    f16x8 bf[10];
    #pragma unroll
    for (int kc = 0; kc < 10; ++kc)
      bf[kc] = *(const f16x8*)&br[(kc*64 + l)*8];
    f32x4 acc[3][3];
    #pragma unroll
    for (int cbl = 0; cbl < 3; ++cbl){
      if (cbl < ncb){
        #pragma unroll
        for (int gate = 0; gate < 3; ++gate){
          int mt = gate*19 + cb0 + cbl;
          f16x8 sa[7];
          #pragma unroll
          for (int kk = 0; kk < 7; ++kk)
            sa[kk] = *(const f16x8*)&WhhP[((size_t)(mt*10 + 3 + kk)*64 + l)*8];
          f16x8 a1 = *(const f16x8*)&Albuf[((mt*2 + 0)*64 + l)*8];
          f16x8 a2 = *(const f16x8*)&Albuf[((mt*2 + 1)*64 + l)*8];
          f32x4 a_ = {0.f, 0.f, 0.f, 0.f};
          a_ = __builtin_amdgcn_mfma_f32_16x16x32_f16(areg[cbl][gate], bf[0], a_, 0, 0, 0);
          a_ = __builtin_amdgcn_mfma_f32_16x16x32_f16(a1, bf[1], a_, 0, 0, 0);
          a_ = __builtin_amdgcn_mfma_f32_16x16x32_f16(a2, bf[2], a_, 0, 0, 0);
          #pragma unroll
          for (int kk = 0; kk < 7; ++kk)
            a_ = __builtin_amdgcn_mfma_f32_16x16x32_f16(sa[kk], bf[3+kk], a_, 0, 0, 0);
          acc[cbl][gate] = a_;
        }
      }
    }
    #pragma unroll
    for (int cbl = 0; cbl < 3; ++cbl){
      if (cbl < ncb){
        int cb = cb0 + cbl;
        f16 hx[4];
        #pragma unroll
        for (int rg = 0; rg < 4; ++rg){
          float rr = sigm_(acc[cbl][0][rg] + (float)giv[cbl][0][rg]);
          float zz = sigm_(acc[cbl][1][rg] + (float)giv[cbl][1][rg]);
          float nn = tanh_((float)giv[cbl][2][rg] + rr*(acc[cbl][2][rg] + bhhN[cbl][rg]));
          float hn = (1.f - zz)*nn + zz*hreg[cbl][rg];
          hreg[cbl][rg] = hn;
          hx[rg] = (f16)hn;
        }
        int c0 = cb*16 + g*4;
        if (bl < 10 && c0 < 300){
          int kc = c0 >> 5, grp2 = (c0 & 31) >> 3, e0 = c0 & 7;
          f16x4 pv = {hx[0], hx[1], hx[2], hx[3]};
          *(f16x4*)&bw[(size_t)((kc*64) + (grp2 << 4) + bl)*8 + e0] = pv;
        }
      }
    }
    __syncthreads();
  }
  #pragma unroll
  for (int cbl = 0; cbl < 3; ++cbl){
    if (cbl < ncb){
      #pragma unroll
      for (int rg = 0; rg < 4; ++rg){
        int c = (cb0 + cbl)*16 + g*4 + rg;
        if (bl < 10 && c < 300) hout[bl*300 + c] = hreg[cbl][rg];
      }
    }
  }
}

// ================= launch =================
extern "C" void kernel_launch(void* const* d_in, const int* in_sizes, int n_in,
                              void* d_out, int out_size, void* d_ws, size_t ws_size,
                              hipStream_t stream)
{
  const float* cs   = (const float*)d_in[0];
  const float* m    = (const float*)d_in[1];
  const float* q    = (const float*)d_in[2];
  const float* mask = (const float*)d_in[3];
  const float* Wb   = (const float*)d_in[4];
  const float* W1   = (const float*)d_in[5];
  const float* b1   = (const float*)d_in[6];
  const float* W2   = (const float*)d_in[7];
  const float* b2   = (const float*)d_in[8];
  const float* Wih  = (const float*)d_in[9];
  const float* Whh  = (const float*)d_in[10];
  const float* bih  = (const float*)d_in[11];
  const float* bhh  = (const float*)d_in[12];
  float* out = (float*)d_out;
  char* ws = (char*)d_ws;
  float* Gs   = (float*)(ws + WS_GS);
  float* QM   = (float*)(ws + WS_QM);
  float* CB   = (float*)(ws + WS_CB);
  f16*   W1T  = (f16*)(ws + WS_W1T);
  f16*   WhhP = (f16*)(ws + WS_WHHP);
  f16*   giP  = (f16*)(ws + WS_GIP);

  k0_prep<<<dim3(1), dim3(512), 0, stream>>>(q, m, W1, b1, QM, CB, W1T);
  k_pack<<<dim3(570), dim3(64), 0, stream>>>(Whh, WhhP);
  k1_attn<<<dim3(256), dim3(512), 0, stream>>>(cs, m, q, mask, Wb, W2, b2, QM, CB, W1T, out);
  k2_softmax<<<dim3(10), dim3(256), 0, stream>>>(out, Gs);
  k3_gi<<<dim3(2048), dim3(256), 0, stream>>>(cs, Gs, Wih, bih, bhh, giP);
  k4_gru<<<dim3(1), dim3(512), 0, stream>>>(WhhP, giP, m, bhh, out + 20480);
}

// Round 2
// 8248.061 us; speedup vs baseline: 2.7010x; 2.7010x over previous
//
#include <hip/hip_runtime.h>
#include <hip/hip_fp16.h>
#include <cstdint>
#include <cstddef>

typedef _Float16 f16;
typedef _Float16 f16x8 __attribute__((ext_vector_type(8)));
typedef _Float16 f16x4 __attribute__((ext_vector_type(4)));
typedef float    f32x4 __attribute__((ext_vector_type(4)));

// ---------------- ws layout (bytes) ----------------
// Gs   f32 [2048][10]                :      0 ..  81920
// QM   f32 [10][16]                  :  81920 ..  82560
// CB   f32 [10][16]                  :  82560 ..  83200
// W1T  f16 [16][5][4][80]            :  83200 .. 134400   (dead after k1)
//   hbuf u64 [2][1280]  (overlay)    :  83200 .. 103680
//   flags u32[20][16]   (overlay)    : 103680 .. 104960
// WhhP f16 [57*10][64][8]            : 134400 .. 718080
// giP  f16 [2048][57][64][4]         : 718080 .. 60486912
#define WS_GS    0u
#define WS_QM    81920u
#define WS_CB    82560u
#define WS_W1T   83200u
#define WS_HBUF  83200u
#define WS_FLAGS 103680u
#define WS_WHHP  134400u
#define WS_GIP   718080u

#define NWG 10
#define HB64 1280   // u64 per parity buffer: 10*64*8 f16 = 10240 B

__device__ __forceinline__ float sigm_(float x){ return 1.0f/(1.0f + __expf(-x)); }
__device__ __forceinline__ float tanh_(float x){
  float ax = fabsf(x);
  float e  = __expf(-2.0f*ax);
  float r  = (1.0f - e)/(1.0f + e);
  return x < 0.0f ? -r : r;
}
__device__ __forceinline__ int imin_(int a,int b){ return a<b?a:b; }

// ================= K0: prep (QM, CB, W1T) =================
__global__ __launch_bounds__(512) void k0_prep(
    const float* __restrict__ q, const float* __restrict__ m,
    const float* __restrict__ W1, const float* __restrict__ b1,
    float* __restrict__ QM, float* __restrict__ CBo, f16* __restrict__ W1T)
{
  int tid = threadIdx.x;
  if (tid < 160){
    int k = tid >> 4, h = tid & 15;
    float acc = 0.f;
    for (int d = 0; d < 300; ++d)
      acc += q[k*300+d]*W1[(2100+d)*16+h] + m[k*300+d]*W1[(2400+d)*16+h];
    QM[tid] = acc;
  } else if (tid < 320){
    int b = (tid-160) >> 4, h = tid & 15;
    float acc = b1[h];
    for (int d = 0; d < 300; ++d)
      acc += m[b*300+d]*W1[(300+d)*16+h] + q[b*300+d]*W1[(600+d)*16+h];
    CBo[tid-160] = acc;
  }
  const int blkoff[5] = {0, 900, 1200, 1500, 1800};
  for (int i = tid; i < 25600; i += 512){
    int ii = i % 80; int r = i / 80;
    int dg = r % 4; r /= 4;
    int blk = r % 5; int h = r / 5;
    int d = dg*80 + ii;
    float v = 0.f;
    if (d < 300) v = W1[(blkoff[blk]+d)*16 + h];
    W1T[i] = (f16)v;
  }
}

// ================= Kpack: Whh -> MFMA A-fragment layout (f16) =================
__global__ __launch_bounds__(64) void k_pack(const float* __restrict__ Whh, f16* __restrict__ WhhP)
{
  int bid = blockIdx.x, l = threadIdx.x;
  int mt = bid / 10, kc = bid % 10;
  int gate = mt / 19, cb = mt % 19;
  int rr = l & 15, grp = l >> 4;
  int c = cb*16 + rr;
  int j = gate*300 + imin_(c, 299);
  f16x8 v;
  #pragma unroll
  for (int e = 0; e < 8; ++e){
    int d = kc*32 + grp*8 + e;
    float x = Whh[(size_t)imin_(d,299)*900 + j];
    v[e] = (f16)((d < 300 && c < 300) ? x : 0.f);
  }
  *(f16x8*)&WhhP[((size_t)bid*64 + l)*8] = v;
}

// ================= K1: attention gate -> G[b][t] (d_out[0:20480]) =================
__global__ __launch_bounds__(512) void k1_attn(
    const float* __restrict__ cs, const float* __restrict__ mI, const float* __restrict__ qI,
    const float* __restrict__ mask, const float* __restrict__ Wb,
    const float* __restrict__ W2, const float* __restrict__ b2,
    const float* __restrict__ QMg, const float* __restrict__ CBg, const f16* __restrict__ W1Tg,
    float* __restrict__ Gout)
{
  __shared__ __align__(16) float q_s[3000];
  __shared__ __align__(16) float m_s[3000];
  __shared__ float Wb_s[3000];
  __shared__ float QM_s[160], CB_s[160], W2_s[16];
  __shared__ __align__(16) f16 W1T_s[25600];
  __shared__ float cwb_s[8][10][10];
  int tid = threadIdx.x;
  for (int i = tid; i < 3000; i += 512){ q_s[i] = qI[i]; m_s[i] = mI[i]; Wb_s[i] = Wb[i]; }
  for (int i = tid; i < 160; i += 512){ QM_s[i] = QMg[i]; CB_s[i] = CBg[i]; }
  if (tid < 16) W2_s[tid] = W2[tid];
  for (int i = tid; i < 25600; i += 512) W1T_s[i] = W1Tg[i];
  __syncthreads();

  int w = tid >> 6, l = tid & 63, dg = l >> 4, lo = l & 15;
  int t = blockIdx.x*8 + w;
  float a[10], cwb[10];
  #pragma unroll
  for (int b = 0; b < 10; ++b){ a[b] = 0.f; cwb[b] = 0.f; }

  for (int i = 0; i < 10; ++i){
    int d0 = dg*80 + i*8;
    const int wbase = lo*1600 + dg*80 + i*8;
    f16x8 wf0 = *(const f16x8*)&W1T_s[wbase + 0*320];
    f16x8 wf1 = *(const f16x8*)&W1T_s[wbase + 1*320];
    f16x8 wf2 = *(const f16x8*)&W1T_s[wbase + 2*320];
    f16x8 wf3 = *(const f16x8*)&W1T_s[wbase + 3*320];
    f16x8 wf4 = *(const f16x8*)&W1T_s[wbase + 4*320];
    int dc0 = imin_(d0, 296), dc1 = imin_(d0 + 4, 296);
    #pragma unroll
    for (int b = 0; b < 10; ++b){
      const float* csb = cs + ((size_t)t*10 + b)*300;
      float4 c0 = *(const float4*)(csb + dc0);
      float4 c1 = *(const float4*)(csb + dc1);
      float4 q0 = *(const float4*)(q_s + b*300 + dc0);
      float4 q1 = *(const float4*)(q_s + b*300 + dc1);
      float4 m0 = *(const float4*)(m_s + b*300 + dc0);
      float4 m1 = *(const float4*)(m_s + b*300 + dc1);
      float cv[8] = {c0.x,c0.y,c0.z,c0.w,c1.x,c1.y,c1.z,c1.w};
      float qv[8] = {q0.x,q0.y,q0.z,q0.w,q1.x,q1.y,q1.z,q1.w};
      float mv[8] = {m0.x,m0.y,m0.z,m0.w,m1.x,m1.y,m1.z,m1.w};
      #pragma unroll
      for (int e = 0; e < 8; ++e){
        int d = d0 + e;
        float cvv = cv[e];
        a[b] += cvv*(float)wf0[e] + (cvv*qv[e])*(float)wf1[e] + (cvv*mv[e])*(float)wf2[e]
              + fabsf(cvv - qv[e])*(float)wf3[e] + fabsf(cvv - mv[e])*(float)wf4[e];
        float wv = Wb_s[imin_(d, 299)*10 + imin_(lo, 9)];
        wv = (lo < 10 && d < 300) ? wv : 0.f;
        cwb[b] += cvv*wv;
      }
    }
  }
  #pragma unroll
  for (int b = 0; b < 10; ++b){
    float v = cwb[b];
    v += __shfl_xor(v, 16, 64);
    v += __shfl_xor(v, 32, 64);
    cwb[b] = v;
  }
  if (dg == 0 && lo < 10){
    #pragma unroll
    for (int b = 0; b < 10; ++b) cwb_s[w][b][lo] = cwb[b];
  }
  __asm__ volatile("s_waitcnt lgkmcnt(0)" ::: "memory");
  __builtin_amdgcn_sched_barrier(0);
  float b2v = b2[0];
  #pragma unroll
  for (int b = 0; b < 10; ++b){
    float cross = 0.f;
    #pragma unroll
    for (int k = 0; k < 10; ++k) cross += cwb_s[w][b][k]*QM_s[k*16 + lo];
    float v = a[b];
    v += __shfl_xor(v, 16, 64);
    v += __shfl_xor(v, 32, 64);
    v += CB_s[b*16 + lo] + cross;
    float tv = tanh_(v)*W2_s[lo];
    tv += __shfl_xor(tv, 1, 64);
    tv += __shfl_xor(tv, 2, 64);
    tv += __shfl_xor(tv, 4, 64);
    tv += __shfl_xor(tv, 8, 64);
    a[b] = sigm_(tv + b2v);
  }
  if (l == 0){
    #pragma unroll
    for (int b = 0; b < 10; ++b) Gout[b*2048 + t] = a[b]*mask[t*10 + b];
  }
}

// ================= K2: softmax over T per b: Gs[t][b] =================
__global__ __launch_bounds__(256) void k2_softmax(const float* __restrict__ G, float* __restrict__ Gs)
{
  int b = blockIdx.x, tid = threadIdx.x;
  __shared__ float red[4];
  float v[8];
  #pragma unroll
  for (int k = 0; k < 8; ++k) v[k] = G[b*2048 + tid + k*256];
  float mx = v[0];
  #pragma unroll
  for (int k = 1; k < 8; ++k) mx = fmaxf(mx, v[k]);
  #pragma unroll
  for (int off = 1; off < 64; off <<= 1) mx = fmaxf(mx, __shfl_xor(mx, off, 64));
  if ((tid & 63) == 0) red[tid >> 6] = mx;
  __syncthreads();
  mx = fmaxf(fmaxf(red[0], red[1]), fmaxf(red[2], red[3]));
  __syncthreads();
  float e[8], s = 0.f;
  #pragma unroll
  for (int k = 0; k < 8; ++k){ e[k] = __expf(v[k]-mx); s += e[k]; }
  #pragma unroll
  for (int off = 1; off < 64; off <<= 1) s += __shfl_xor(s, off, 64);
  if ((tid & 63) == 0) red[tid >> 6] = s;
  __syncthreads();
  s = red[0]+red[1]+red[2]+red[3];
  float inv = 1.0f / s;
  #pragma unroll
  for (int k = 0; k < 8; ++k) Gs[(tid + k*256)*10 + b] = e[k]*inv;
}

// ================= K3: gi[t] = seq[t] @ Wih + bih (+bhh folded for r,z) =================
__global__ __launch_bounds__(256) void k3_gi(
    const float* __restrict__ cs, const float* __restrict__ Gs,
    const float* __restrict__ Wih, const float* __restrict__ bih, const float* __restrict__ bhh,
    f16* __restrict__ giP)
{
  int t = blockIdx.x, tid = threadIdx.x;
  __shared__ __align__(16) float sfT[300*16];
  for (int i = tid; i < 3000; i += 256){
    int d = i / 10, bcol = i % 10;
    int jj = d % 10;
    sfT[d*16 + bcol] = Gs[t*10 + jj] * cs[((size_t)t*10 + jj)*300 + bcol*30 + d/10];
  }
  __syncthreads();
  float acc[4][10];
  #pragma unroll
  for (int jp = 0; jp < 4; ++jp)
    #pragma unroll
    for (int b = 0; b < 10; ++b) acc[jp][b] = 0.f;
  for (int d = 0; d < 300; ++d){
    float4 s0 = *(const float4*)&sfT[d*16 + 0];
    float4 s1 = *(const float4*)&sfT[d*16 + 4];
    float4 s2 = *(const float4*)&sfT[d*16 + 8];
    float sb[10] = {s0.x,s0.y,s0.z,s0.w, s1.x,s1.y,s1.z,s1.w, s2.x,s2.y};
    #pragma unroll
    for (int jp = 0; jp < 4; ++jp){
      int j = jp*256 + tid;
      float wv = Wih[(size_t)d*900 + imin_(j, 899)];
      wv = (j < 900) ? wv : 0.f;
      #pragma unroll
      for (int b = 0; b < 10; ++b) acc[jp][b] += wv * sb[b];
    }
  }
  #pragma unroll
  for (int jp = 0; jp < 4; ++jp){
    int j = jp*256 + tid;
    if (j < 900){
      int gate = j / 300, c = j - gate*300;
      int cb = c >> 4, rr = c & 15;
      int mt = gate*19 + cb, g = rr >> 2, er = rr & 3;
      float bias = bih[j] + (j < 600 ? bhh[j] : 0.f);
      size_t base = ((size_t)t*57 + mt)*256;
      #pragma unroll
      for (int b = 0; b < 10; ++b)
        giP[base + (size_t)(((g<<4)|b)*4 + er)] = (f16)(acc[jp][b] + bias);
    }
  }
}

// ================= K4: sequential GRU, 10 WGs, Whh resident in VGPRs =================
// 19 cb-units (16 output c's x 3 gates). WG w owns cb = 2w, 2w+1. 6 waves/WG:
// wave = gate*2 + cbl, one 16x16 tile, K=320 -> 10 A-frags = 40 VGPRs resident.
// Cross-WG h exchange via agent-scope atomics on hbuf (B-frag layout, parity
// double-buffered) + per-wave release flags; readers spin then atomic-load.
__global__ __launch_bounds__(384) void k4_gru(
    const f16* __restrict__ WhhP, const f16* __restrict__ giP,
    const float* __restrict__ mI, const float* __restrict__ bhh,
    unsigned long long* hbuf, unsigned int* flags, float* hout)
{
  __shared__ f32x4 accs[2][2][64];     // [gate-1][cbl][lane]
  __shared__ volatile int dead;
  int wgid = blockIdx.x, tid = threadIdx.x;
  int w = tid >> 6, l = tid & 63;
  int gate = w >> 1, cbl = w & 1;
  int cb = wgid*2 + cbl;
  bool active = (cb < 19);
  int bl = l & 15, g = l >> 4;
  bool comb = (gate == 0);
  if (tid == 0) dead = 0;

  // resident A fragments (40 VGPRs)
  f16x8 areg[10];
  if (active){
    int mt = gate*19 + cb;
    #pragma unroll
    for (int kc = 0; kc < 10; ++kc)
      areg[kc] = *(const f16x8*)&WhhP[((size_t)(mt*10+kc)*64 + l)*8];
  }
  int c0 = cb*16 + g*4;
  bool wv = comb && active && (c0 < 300);   // this lane owns valid output rows
  float hreg[4], bhhN[4];
  #pragma unroll
  for (int rg = 0; rg < 4; ++rg){
    int c = c0 + rg;
    hreg[rg] = (wv && bl < 10) ? mI[bl*300 + imin_(c,299)] : 0.f;
    bhhN[rg] = wv ? bhh[600 + imin_(c,299)] : 0.f;
  }
  __syncthreads();

  // publish h0 (pads were pre-zeroed by memset)
  if (wv && bl < 10){
    union { f16 h4[4]; unsigned long long u; } pk;
    #pragma unroll
    for (int rg = 0; rg < 4; ++rg) pk.h4[rg] = (f16)hreg[rg];
    int kc = c0 >> 5, grp = (c0 & 31) >> 3, e0 = c0 & 7;
    __hip_atomic_store(&hbuf[(size_t)(kc*64 + grp*16 + bl)*2 + (e0>>2)], pk.u,
                       __ATOMIC_RELAXED, __HIP_MEMORY_SCOPE_AGENT);
  }
  if (comb && l == 0)
    __hip_atomic_store(&flags[(wgid*2 + cbl)*16], 1u, __ATOMIC_RELEASE, __HIP_MEMORY_SCOPE_AGENT);

  for (int t = 0; t < 2048; ++t){
    // ---- wait until all 20 producer waves have published h_t ----
    unsigned tgt = (unsigned)(t + 1);
    if (l < 2*NWG && !dead){
      int it = 0;
      while (__hip_atomic_load(&flags[l*16], __ATOMIC_RELAXED, __HIP_MEMORY_SCOPE_AGENT) < tgt){
        if (++it > 20000000) { dead = 1; break; }
      }
    }
    __builtin_amdgcn_sched_barrier(0);

    f32x4 accv = {0.f,0.f,0.f,0.f};
    f16x4 gr = {}, gz = {}, gn = {};
    if (active){
      // h_t B-fragments via coherent (agent) loads
      const unsigned long long* hb = hbuf + (size_t)(t & 1)*HB64;
      f16x8 bf[10];
      #pragma unroll
      for (int kc = 0; kc < 10; ++kc){
        union { unsigned long long u[2]; f16x8 v; } cv;
        cv.u[0] = __hip_atomic_load(&hb[(size_t)(kc*64 + l)*2 + 0], __ATOMIC_RELAXED, __HIP_MEMORY_SCOPE_AGENT);
        cv.u[1] = __hip_atomic_load(&hb[(size_t)(kc*64 + l)*2 + 1], __ATOMIC_RELAXED, __HIP_MEMORY_SCOPE_AGENT);
        bf[kc] = cv.v;
      }
      if (wv){  // gi for this step (issued after bf -> stays in flight during MFMA)
        const f16* gp = giP + (size_t)t*57*256;
        gr = *(const f16x4*)&gp[(size_t)((0*19+cb)*256) + l*4];
        gz = *(const f16x4*)&gp[(size_t)((1*19+cb)*256) + l*4];
        gn = *(const f16x4*)&gp[(size_t)((2*19+cb)*256) + l*4];
      }
      f32x4 a0 = {0.f,0.f,0.f,0.f}, a1 = {0.f,0.f,0.f,0.f};
      #pragma unroll
      for (int kc = 0; kc < 5; ++kc){
        a0 = __builtin_amdgcn_mfma_f32_16x16x32_f16(areg[kc],   bf[kc],   a0, 0, 0, 0);
        a1 = __builtin_amdgcn_mfma_f32_16x16x32_f16(areg[kc+5], bf[kc+5], a1, 0, 0, 0);
      }
      accv = a0 + a1;
      if (gate > 0) accs[gate-1][cbl][l] = accv;
    }
    __syncthreads();

    if (comb){
      if (active){
        f32x4 az = accs[0][cbl][l], an = accs[1][cbl][l];
        union { f16 h4[4]; unsigned long long u; } pk;
        #pragma unroll
        for (int rg = 0; rg < 4; ++rg){
          float r  = sigm_(accv[rg] + (float)gr[rg]);
          float z  = sigm_(az[rg]   + (float)gz[rg]);
          float n  = tanh_((float)gn[rg] + r*(an[rg] + bhhN[rg]));
          float hn = (1.f - z)*n + z*hreg[rg];
          hreg[rg] = hn;
          pk.h4[rg] = (f16)hn;
        }
        if (wv && bl < 10){
          int kc = c0 >> 5, grp = (c0 & 31) >> 3, e0 = c0 & 7;
          __hip_atomic_store(&hbuf[(size_t)((t+1)&1)*HB64 + (size_t)(kc*64 + grp*16 + bl)*2 + (e0>>2)],
                             pk.u, __ATOMIC_RELAXED, __HIP_MEMORY_SCOPE_AGENT);
        }
      }
      if (l == 0)
        __hip_atomic_store(&flags[(wgid*2 + cbl)*16], (unsigned)(t + 2),
                           __ATOMIC_RELEASE, __HIP_MEMORY_SCOPE_AGENT);
    }
  }
  // final h = h_2048 (exact f32 slice in combiner registers)
  if (wv && bl < 10){
    #pragma unroll
    for (int rg = 0; rg < 4; ++rg)
      hout[bl*300 + c0 + rg] = hreg[rg];
  }
}

// ================= launch =================
extern "C" void kernel_launch(void* const* d_in, const int* in_sizes, int n_in,
                              void* d_out, int out_size, void* d_ws, size_t ws_size,
                              hipStream_t stream)
{
  const float* cs   = (const float*)d_in[0];
  const float* m    = (const float*)d_in[1];
  const float* q    = (const float*)d_in[2];
  const float* mask = (const float*)d_in[3];
  const float* Wb   = (const float*)d_in[4];
  const float* W1   = (const float*)d_in[5];
  const float* b1   = (const float*)d_in[6];
  const float* W2   = (const float*)d_in[7];
  const float* b2   = (const float*)d_in[8];
  const float* Wih  = (const float*)d_in[9];
  const float* Whh  = (const float*)d_in[10];
  const float* bih  = (const float*)d_in[11];
  const float* bhh  = (const float*)d_in[12];
  float* out = (float*)d_out;
  char* ws = (char*)d_ws;
  float* Gs   = (float*)(ws + WS_GS);
  float* QM   = (float*)(ws + WS_QM);
  float* CB   = (float*)(ws + WS_CB);
  f16*   W1T  = (f16*)(ws + WS_W1T);
  f16*   WhhP = (f16*)(ws + WS_WHHP);
  f16*   giP  = (f16*)(ws + WS_GIP);
  unsigned long long* hbuf = (unsigned long long*)(ws + WS_HBUF);
  unsigned int* flags = (unsigned int*)(ws + WS_FLAGS);

  k0_prep<<<dim3(1), dim3(512), 0, stream>>>(q, m, W1, b1, QM, CB, W1T);
  k_pack<<<dim3(570), dim3(64), 0, stream>>>(Whh, WhhP);
  k1_attn<<<dim3(256), dim3(512), 0, stream>>>(cs, m, q, mask, Wb, W2, b2, QM, CB, W1T, out);
  k2_softmax<<<dim3(10), dim3(256), 0, stream>>>(out, Gs);
  k3_gi<<<dim3(2048), dim3(256), 0, stream>>>(cs, Gs, Wih, bih, bhh, giP);
  // W1T region is dead after k1 -> reuse for hbuf (zeroed pads) + flags
  hipMemsetAsync(ws + WS_HBUF, 0, 20480 + 1280, stream);
  k4_gru<<<dim3(NWG), dim3(384), 0, stream>>>(WhhP, giP, m, bhh, hbuf, flags, out + 20480);
}